// Round 1
// baseline (100.867 us; speedup 1.0000x reference)
//
#include <hip/hip_runtime.h>
#include <hip/hip_fp16.h>

typedef _Float16 h16;
typedef __attribute__((ext_vector_type(8))) _Float16 h16x8;
typedef __attribute__((ext_vector_type(4))) float f32x4;

#define DIM   1024
#define SEQ   2048
#define NKV   2
#define HD    64
#define WIN   256
#define HALFW 128
#define NQKV  1280      // 1024 q + 128 k + 128 v
#define KROWS 272       // 16 + 256 staged key rows per q-tile
#define VSTR  296       // padded Vt/P row stride (2-way-conflict-free)

// ---------------- prep: x fp32 -> fp16, concat qkv bias ----------------
__global__ void prep_kernel(const float* __restrict__ x,
                            const float* __restrict__ bq,
                            const float* __restrict__ bk,
                            const float* __restrict__ bv,
                            h16* __restrict__ xh, float* __restrict__ bqkv)
{
    int i = blockIdx.x * 256 + threadIdx.x;          // 524288 items x 8 elems
    size_t base = (size_t)i * 8;
    float4 a = *(const float4*)(x + base);
    float4 b = *(const float4*)(x + base + 4);
    h16x8 o = { (h16)a.x,(h16)a.y,(h16)a.z,(h16)a.w,
                (h16)b.x,(h16)b.y,(h16)b.z,(h16)b.w };
    *(h16x8*)(xh + base) = o;
    if (i < NQKV) {
        float v = (i < DIM) ? bq[i] : (i < DIM+128 ? bk[i-DIM] : bv[i-DIM-128]);
        bqkv[i] = v;
    }
}

// ------------- weight transpose: dst[n][k] fp16 from src[k][n] fp32 -------------
__global__ void transpose_qkv_kernel(const float* __restrict__ Wq,
                                     const float* __restrict__ Wk,
                                     const float* __restrict__ Wv,
                                     h16* __restrict__ dst)
{
    __shared__ float tile[32][33];
    int n0 = blockIdx.x * 32, k0 = blockIdx.y * 32;
    int tx = threadIdx.x, ty = threadIdx.y;          // 32 x 8
    const float* src; int ldn, noff;
    if (n0 < DIM)          { src = Wq; ldn = DIM; noff = n0; }
    else if (n0 < DIM+128) { src = Wk; ldn = 128; noff = n0 - DIM; }
    else                   { src = Wv; ldn = 128; noff = n0 - DIM - 128; }
#pragma unroll
    for (int i = 0; i < 4; ++i)
        tile[ty + 8*i][tx] = src[(size_t)(k0 + ty + 8*i)*ldn + noff + tx];
    __syncthreads();
#pragma unroll
    for (int i = 0; i < 4; ++i)
        dst[(size_t)(n0 + ty + 8*i)*DIM + k0 + tx] = (h16)tile[tx][ty + 8*i];
}

__global__ void transpose_wo_kernel(const float* __restrict__ Wo, h16* __restrict__ dst)
{
    __shared__ float tile[32][33];
    int n0 = blockIdx.x * 32, k0 = blockIdx.y * 32;
    int tx = threadIdx.x, ty = threadIdx.y;
#pragma unroll
    for (int i = 0; i < 4; ++i)
        tile[ty + 8*i][tx] = Wo[(size_t)(k0 + ty + 8*i)*DIM + n0 + tx];
    __syncthreads();
#pragma unroll
    for (int i = 0; i < 4; ++i)
        dst[(size_t)(n0 + ty + 8*i)*DIM + k0 + tx] = (h16)tile[tx][ty + 8*i];
}

// ------------- GEMM (m97 structure): C = A[M][K] * Bt[N][K]^T + bias -------------
// MODE 0: scatter epilogue -> q [m][n], k [b][g][s][d], vt [b][g][d][s], fp16
// MODE 1: fp32 out + bias
template<int MODE>
__global__ __launch_bounds__(256)
void gemm_kernel(const h16* __restrict__ A, const h16* __restrict__ Bt,
                 const float* __restrict__ bias,
                 h16* __restrict__ qo, h16* __restrict__ ko, h16* __restrict__ vto,
                 float* __restrict__ co, int K)
{
    __shared__ __align__(16) h16 As[128*32];
    __shared__ __align__(16) h16 Bs[128*32];
    const int m0 = blockIdx.y * 128, n0 = blockIdx.x * 128;
    const int tid = threadIdx.x, lane = tid & 63, wid = tid >> 6;
    const int wr = wid >> 1, wc = wid & 1;
    f32x4 acc[4][4] = {};
    for (int kk = 0; kk < K; kk += 32) {
#pragma unroll
        for (int i = 0; i < 2; ++i) {
            int slot = wid*128 + i*64 + lane;
            int row = slot >> 2, c8 = (slot & 3) * 8;
            __builtin_amdgcn_global_load_lds(
                (const __attribute__((address_space(1))) void*)(A + (size_t)(m0 + row)*K + kk + c8),
                (__attribute__((address_space(3))) void*)(As + slot*8), 16, 0, 0);
            __builtin_amdgcn_global_load_lds(
                (const __attribute__((address_space(1))) void*)(Bt + (size_t)(n0 + row)*K + kk + c8),
                (__attribute__((address_space(3))) void*)(Bs + slot*8), 16, 0, 0);
        }
        __syncthreads();
        h16x8 a[4], b[4];
#pragma unroll
        for (int mi = 0; mi < 4; ++mi)
            a[mi] = *(const h16x8*)(As + (wr*64 + mi*16 + (lane & 15))*32 + (lane >> 4)*8);
#pragma unroll
        for (int ni = 0; ni < 4; ++ni)
            b[ni] = *(const h16x8*)(Bs + (wc*64 + ni*16 + (lane & 15))*32 + (lane >> 4)*8);
#pragma unroll
        for (int mi = 0; mi < 4; ++mi)
#pragma unroll
            for (int ni = 0; ni < 4; ++ni)
                acc[mi][ni] = __builtin_amdgcn_mfma_f32_16x16x32_f16(a[mi], b[ni], acc[mi][ni], 0, 0, 0);
        __syncthreads();
    }
#pragma unroll
    for (int ni = 0; ni < 4; ++ni) {
        int n = n0 + wc*64 + ni*16 + (lane & 15);
        float bv = bias[n];
#pragma unroll
        for (int mi = 0; mi < 4; ++mi) {
            int mb = m0 + wr*64 + mi*16 + (lane >> 4)*4;
#pragma unroll
            for (int r = 0; r < 4; ++r) {
                int m = mb + r;
                float v = acc[mi][ni][r] + bv;
                if (MODE == 1) {
                    co[(size_t)m*DIM + n] = v;
                } else {
                    h16 hv = (h16)v;
                    if (n < DIM) {
                        qo[(size_t)m*DIM + n] = hv;
                    } else {
                        int nn = n - DIM;
                        int bi2 = m >> 11, s = m & 2047;
                        if (nn < 128) {
                            int g = nn >> 6, d = nn & 63;
                            ko[(((size_t)(bi2*NKV + g))*SEQ + s)*HD + d] = hv;
                        } else {
                            nn -= 128;
                            int g = nn >> 6, d = nn & 63;
                            vto[(((size_t)(bi2*NKV + g))*HD + d)*SEQ + s] = hv;
                        }
                    }
                }
            }
        }
    }
}

// ------------- sliding-window attention -------------
// block = (q-tile of 16, g, b); 8 waves, wave = head (h = g*8 + wid)
// K_lds [272][64] XOR-swizzled; Vt_lds [64][296]; P_lds [8][16][296]
__global__ __launch_bounds__(512)
void attn_kernel(const h16* __restrict__ qb, const h16* __restrict__ kb,
                 const h16* __restrict__ vtb, h16* __restrict__ ob)
{
    extern __shared__ char smem[];
    h16* Ks  = (h16*)smem;                         // 272*64*2 = 34816 B
    h16* Vts = (h16*)(smem + 34816);               // 64*296*2 = 37888 B
    h16* Ps  = (h16*)(smem + 34816 + 37888);       // 8*16*296*2 = 75776 B
    const int tid = threadIdx.x, lane = tid & 63, wid = tid >> 6;
    const int qt = blockIdx.x, g = blockIdx.y, bi = blockIdx.z;
    const int s0 = qt * 16;
    const size_t kvbase = ((size_t)(bi*NKV + g)) * SEQ * HD;

    // stage K rows s0-128 .. s0+143 (zeros outside sequence), XOR-swizzled chunks
    for (int slot = tid; slot < KROWS*8; slot += 512) {
        int row = slot >> 3, cc = slot & 7;
        int kpos = s0 - HALFW + row;
        h16x8 val = {0,0,0,0,0,0,0,0};
        if (kpos >= 0 && kpos < SEQ)
            val = *(const h16x8*)(kb + kvbase + (size_t)kpos*HD + cc*8);
        *(h16x8*)(Ks + row*64 + ((cc ^ (row & 7)) * 8)) = val;
    }
    // stage Vt [dim][key], zero-padded cols
    for (int slot = tid; slot < 64*37; slot += 512) {
        int row = slot / 37, cc = slot - row*37;
        int c0 = cc * 8;
        int kp0 = s0 - HALFW + c0;
        h16x8 val = {0,0,0,0,0,0,0,0};
        if (c0 + 7 < KROWS && kp0 >= 0 && kp0 + 7 < SEQ) {
            val = *(const h16x8*)(vtb + kvbase + (size_t)row*SEQ + kp0);
        } else {
#pragma unroll
            for (int j = 0; j < 8; ++j) {
                int col = c0 + j, kp = kp0 + j;
                val[j] = (col < KROWS && kp >= 0 && kp < SEQ)
                         ? vtb[kvbase + (size_t)row*SEQ + kp] : (h16)0;
            }
        }
        *(h16x8*)(Vts + row*VSTR + c0) = val;
    }
    // zero own wave's P pad cols [272..288)
    h16* P = Ps + wid * 16 * VSTR;
    for (int i = lane; i < 256; i += 64) {
        int r = i >> 4, c = KROWS + (i & 15);
        P[r*VSTR + c] = (h16)0;
    }
    // Q fragments straight from global
    const int h = g*8 + wid;
    h16x8 aq[2];
#pragma unroll
    for (int c = 0; c < 2; ++c)
        aq[c] = *(const h16x8*)(qb + ((size_t)(bi*SEQ + s0 + (lane & 15)))*DIM
                                + h*HD + c*32 + (lane >> 4)*8);
    __syncthreads();

    // scores: 17 x 16x16 tiles over 272 keys
    f32x4 sc[17];
#pragma unroll
    for (int t = 0; t < 17; ++t) {
        f32x4 z = {0.f,0.f,0.f,0.f};
#pragma unroll
        for (int c = 0; c < 2; ++c) {
            int key = t*16 + (lane & 15);
            h16x8 bk = *(const h16x8*)(Ks + key*64 + (((c*4 + (lane >> 4)) ^ (key & 7)) * 8));
            z = __builtin_amdgcn_mfma_f32_16x16x32_f16(aq[c], bk, z, 0, 0, 0);
        }
        sc[t] = z;
    }

    // mask (window: row <= col <= row+255) + wave-parallel softmax
    const int colbase = lane & 15;
    const int rowbase = (lane >> 4) * 4;
    float mx[4] = {-1e30f,-1e30f,-1e30f,-1e30f};
#pragma unroll
    for (int t = 0; t < 17; ++t)
#pragma unroll
        for (int r = 0; r < 4; ++r) {
            int col = t*16 + colbase, row = rowbase + r;
            float v = (col >= row && col <= row + 255) ? sc[t][r] : -1e30f;
            sc[t][r] = v;
            mx[r] = fmaxf(mx[r], v);
        }
#pragma unroll
    for (int r = 0; r < 4; ++r) {
        mx[r] = fmaxf(mx[r], __shfl_xor(mx[r], 8));
        mx[r] = fmaxf(mx[r], __shfl_xor(mx[r], 4));
        mx[r] = fmaxf(mx[r], __shfl_xor(mx[r], 2));
        mx[r] = fmaxf(mx[r], __shfl_xor(mx[r], 1));
    }
    float sum[4] = {0.f,0.f,0.f,0.f};
#pragma unroll
    for (int t = 0; t < 17; ++t)
#pragma unroll
        for (int r = 0; r < 4; ++r) {
            float p = __expf(sc[t][r] - mx[r]);
            sc[t][r] = p;
            sum[r] += p;
        }
#pragma unroll
    for (int r = 0; r < 4; ++r) {
        sum[r] += __shfl_xor(sum[r], 8);
        sum[r] += __shfl_xor(sum[r], 4);
        sum[r] += __shfl_xor(sum[r], 2);
        sum[r] += __shfl_xor(sum[r], 1);
    }
    float inv[4];
#pragma unroll
    for (int r = 0; r < 4; ++r) inv[r] = 1.0f / sum[r];

    // write P (C-layout -> row-major [query][key]) as fp16
#pragma unroll
    for (int t = 0; t < 17; ++t)
#pragma unroll
        for (int r = 0; r < 4; ++r)
            P[(rowbase + r)*VSTR + t*16 + colbase] = (h16)(sc[t][r] * inv[r]);

    // PV: (16x288) x (288x64)
    f32x4 ao[4] = {};
#pragma unroll
    for (int c = 0; c < 9; ++c) {
        h16x8 pa = *(const h16x8*)(P + (lane & 15)*VSTR + c*32 + (lane >> 4)*8);
#pragma unroll
        for (int t2 = 0; t2 < 4; ++t2) {
            h16x8 vb = *(const h16x8*)(Vts + (t2*16 + (lane & 15))*VSTR + c*32 + (lane >> 4)*8);
            ao[t2] = __builtin_amdgcn_mfma_f32_16x16x32_f16(pa, vb, ao[t2], 0, 0, 0);
        }
    }
    // epilogue: attn out [b*2048+s][h*64+d] fp16
#pragma unroll
    for (int t2 = 0; t2 < 4; ++t2)
#pragma unroll
        for (int r = 0; r < 4; ++r)
            ob[((size_t)(bi*SEQ + s0 + rowbase + r))*DIM + h*HD + t2*16 + colbase]
                = (h16)ao[t2][r];
}

extern "C" void kernel_launch(void* const* d_in, const int* in_sizes, int n_in,
                              void* d_out, int out_size, void* d_ws, size_t ws_size,
                              hipStream_t stream)
{
    const float* x  = (const float*)d_in[0];
    const float* Wq = (const float*)d_in[1];
    const float* bq = (const float*)d_in[2];
    const float* Wk = (const float*)d_in[3];
    const float* bk = (const float*)d_in[4];
    const float* Wv = (const float*)d_in[5];
    const float* bv = (const float*)d_in[6];
    const float* Wo = (const float*)d_in[7];
    const float* bo = (const float*)d_in[8];
    float* out = (float*)d_out;
    char* ws = (char*)d_ws;

    h16*   xh    = (h16*)(ws);                 //  8388608 B  x fp16 [4096][1024]
    h16*   wqkvt = (h16*)(ws + 8388608);       //  2621440 B  Wqkv^T [1280][1024]
    h16*   wot   = (h16*)(ws + 11010048);      //  2097152 B  Wo^T [1024][1024]
    float* bqkv  = (float*)(ws + 13107200);    //     5120 B
    h16*   q_b   = (h16*)(ws + 13112320);      //  8388608 B  q [4096][1024]
    h16*   k_b   = (h16*)(ws + 21500928);      //  1048576 B  k [b][g][s][64]
    h16*   vt_b  = (h16*)(ws + 22549504);      //  1048576 B  v^T [b][g][64][s]
    h16*   att_b = (h16*)(ws + 23598080);      //  8388608 B  attn out [4096][1024]

    prep_kernel<<<2048, 256, 0, stream>>>(x, bq, bk, bv, xh, bqkv);
    transpose_qkv_kernel<<<dim3(40,32), dim3(32,8), 0, stream>>>(Wq, Wk, Wv, wqkvt);
    transpose_wo_kernel<<<dim3(32,32), dim3(32,8), 0, stream>>>(Wo, wot);
    gemm_kernel<0><<<dim3(10,32), 256, 0, stream>>>(xh, wqkvt, bqkv,
                                                    q_b, k_b, vt_b, nullptr, DIM);
    hipFuncSetAttribute((const void*)attn_kernel,
                        hipFuncAttributeMaxDynamicSharedMemorySize, 148480);
    attn_kernel<<<dim3(128,2,2), 512, 148480, stream>>>(q_b, k_b, vt_b, att_b);
    gemm_kernel<1><<<dim3(8,32), 256, 0, stream>>>(att_b, wot, bo,
                                                   nullptr, nullptr, nullptr, out, DIM);
}

// Round 2
// 95.077 us; speedup vs baseline: 1.0609x; 1.0609x over previous
//
#include <hip/hip_runtime.h>
#include <hip/hip_fp16.h>

typedef _Float16 h16;
typedef __attribute__((ext_vector_type(8))) _Float16 h16x8;
typedef __attribute__((ext_vector_type(4))) float f32x4;

#define DIM   1024
#define SEQ   2048
#define NKV   2
#define HD    64
#define WIN   256
#define HALFW 128
#define NQKV  1280      // 1024 q + 128 k + 128 v
#define KSTG  288       // staged key rows per 32-query block
#define KCOLS 272       // keys per 16-query strip
#define VSTR  296       // padded P row stride

// ---------------- fused preprocess ----------------
// blocks [0,2048): x fp32->fp16 (+bias concat)
// blocks [2048,3328): Wq|Wk|Wv transpose -> wqkvt [1280][1024] fp16
// blocks [3328,4352): Wo transpose -> wot [1024][1024] fp16
__global__ void preprocess_kernel(const float* __restrict__ x,
                                  const float* __restrict__ bq,
                                  const float* __restrict__ bk,
                                  const float* __restrict__ bv,
                                  const float* __restrict__ Wq,
                                  const float* __restrict__ Wk,
                                  const float* __restrict__ Wv,
                                  const float* __restrict__ Wo,
                                  h16* __restrict__ xh, float* __restrict__ bqkv,
                                  h16* __restrict__ wqkvt, h16* __restrict__ wot)
{
    __shared__ float tile[32][33];
    const int tid = threadIdx.x;
    const int blk = blockIdx.x;
    if (blk < 2048) {
        int i = blk * 256 + tid;
        size_t base = (size_t)i * 8;
        float4 a = *(const float4*)(x + base);
        float4 b = *(const float4*)(x + base + 4);
        h16x8 o = { (h16)a.x,(h16)a.y,(h16)a.z,(h16)a.w,
                    (h16)b.x,(h16)b.y,(h16)b.z,(h16)b.w };
        *(h16x8*)(xh + base) = o;
        if (i < NQKV) {
            float v = (i < DIM) ? bq[i] : (i < DIM+128 ? bk[i-DIM] : bv[i-DIM-128]);
            bqkv[i] = v;
        }
        return;
    }
    const int tx = tid & 31, ty = tid >> 5;
    if (blk < 2048 + 1280) {
        int bid = blk - 2048;
        int n0 = (bid % 40) * 32, k0 = (bid / 40) * 32;
        const float* src; int ldn, noff;
        if (n0 < DIM)          { src = Wq; ldn = DIM; noff = n0; }
        else if (n0 < DIM+128) { src = Wk; ldn = 128; noff = n0 - DIM; }
        else                   { src = Wv; ldn = 128; noff = n0 - DIM - 128; }
#pragma unroll
        for (int i = 0; i < 4; ++i)
            tile[ty + 8*i][tx] = src[(size_t)(k0 + ty + 8*i)*ldn + noff + tx];
        __syncthreads();
#pragma unroll
        for (int i = 0; i < 4; ++i)
            wqkvt[(size_t)(n0 + ty + 8*i)*DIM + k0 + tx] = (h16)tile[tx][ty + 8*i];
    } else {
        int bid = blk - 3328;
        int n0 = (bid % 32) * 32, k0 = (bid / 32) * 32;
#pragma unroll
        for (int i = 0; i < 4; ++i)
            tile[ty + 8*i][tx] = Wo[(size_t)(k0 + ty + 8*i)*DIM + n0 + tx];
        __syncthreads();
#pragma unroll
        for (int i = 0; i < 4; ++i)
            wot[(size_t)(n0 + ty + 8*i)*DIM + k0 + tx] = (h16)tile[tx][ty + 8*i];
    }
}

// ------------- GEMM: C = A[M][K] * Bt[N][K]^T + bias, BK=64, swizzled LDS -------------
// MODE 0: scatter epilogue -> q [m][n], k [b][g][s][d], vt [b][g][d][s], fp16
// MODE 1: fp32 out + bias
template<int MODE>
__global__ __launch_bounds__(256)
void gemm_kernel(const h16* __restrict__ A, const h16* __restrict__ Bt,
                 const float* __restrict__ bias,
                 h16* __restrict__ qo, h16* __restrict__ ko, h16* __restrict__ vto,
                 float* __restrict__ co, int K)
{
    __shared__ __align__(16) h16 As[128*64];
    __shared__ __align__(16) h16 Bs[128*64];
    const int m0 = blockIdx.y * 128, n0 = blockIdx.x * 128;
    const int tid = threadIdx.x, lane = tid & 63, wid = tid >> 6;
    const int wr = wid >> 1, wc = wid & 1;
    f32x4 acc[4][4] = {};
    for (int kk = 0; kk < K; kk += 64) {
#pragma unroll
        for (int i = 0; i < 4; ++i) {
            int slot = wid*256 + i*64 + lane;          // 0..1023, lane-contiguous
            int row = slot >> 3, cc = slot & 7;
            int scol = (cc ^ (row & 7)) * 8;           // pre-swizzled global source
            __builtin_amdgcn_global_load_lds(
                (const __attribute__((address_space(1))) void*)(A + (size_t)(m0 + row)*K + kk + scol),
                (__attribute__((address_space(3))) void*)(As + slot*8), 16, 0, 0);
            __builtin_amdgcn_global_load_lds(
                (const __attribute__((address_space(1))) void*)(Bt + (size_t)(n0 + row)*K + kk + scol),
                (__attribute__((address_space(3))) void*)(Bs + slot*8), 16, 0, 0);
        }
        __syncthreads();
#pragma unroll
        for (int k2 = 0; k2 < 2; ++k2) {
            h16x8 a[4], b[4];
#pragma unroll
            for (int mi = 0; mi < 4; ++mi) {
                int row = wr*64 + mi*16 + (lane & 15);
                int cc = (k2*4 + (lane >> 4)) ^ (row & 7);
                a[mi] = *(const h16x8*)(As + row*64 + cc*8);
            }
#pragma unroll
            for (int ni = 0; ni < 4; ++ni) {
                int row = wc*64 + ni*16 + (lane & 15);
                int cc = (k2*4 + (lane >> 4)) ^ (row & 7);
                b[ni] = *(const h16x8*)(Bs + row*64 + cc*8);
            }
#pragma unroll
            for (int mi = 0; mi < 4; ++mi)
#pragma unroll
                for (int ni = 0; ni < 4; ++ni)
                    acc[mi][ni] = __builtin_amdgcn_mfma_f32_16x16x32_f16(a[mi], b[ni], acc[mi][ni], 0, 0, 0);
        }
        __syncthreads();
    }
#pragma unroll
    for (int ni = 0; ni < 4; ++ni) {
        int n = n0 + wc*64 + ni*16 + (lane & 15);
        float bv = bias[n];
#pragma unroll
        for (int mi = 0; mi < 4; ++mi) {
            int mb = m0 + wr*64 + mi*16 + (lane >> 4)*4;
#pragma unroll
            for (int r = 0; r < 4; ++r) {
                int m = mb + r;
                float v = acc[mi][ni][r] + bv;
                if (MODE == 1) {
                    co[(size_t)m*DIM + n] = v;
                } else {
                    h16 hv = (h16)v;
                    if (n < DIM) {
                        qo[(size_t)m*DIM + n] = hv;
                    } else {
                        int nn = n - DIM;
                        int bi2 = m >> 11, s = m & 2047;
                        if (nn < 128) {
                            int g = nn >> 6, d = nn & 63;
                            ko[(((size_t)(bi2*NKV + g))*SEQ + s)*HD + d] = hv;
                        } else {
                            nn -= 128;
                            int g = nn >> 6, d = nn & 63;
                            vto[(((size_t)(bi2*NKV + g))*HD + d)*SEQ + s] = hv;
                        }
                    }
                }
            }
        }
    }
}

// ------------- sliding-window attention -------------
// block = (q-tile of 32, g, b) -> grid 64x2x2 = 256; 8 waves, wave = head
// K_lds [288][64] XOR-swizzled; V read direct from global (L1/L2-resident);
// P_lds per wave [16][296], reused across 2 strips of 16 queries.
__global__ __launch_bounds__(512)
void attn_kernel(const h16* __restrict__ qb, const h16* __restrict__ kb,
                 const h16* __restrict__ vtb, h16* __restrict__ ob)
{
    extern __shared__ char smem[];
    h16* Ks = (h16*)smem;                         // 288*64*2 = 36864 B
    h16* Ps = (h16*)(smem + 36864);               // 8*16*296*2 = 75776 B
    const int tid = threadIdx.x, lane = tid & 63, wid = tid >> 6;
    const int qt = blockIdx.x, g = blockIdx.y, bi = blockIdx.z;
    const int s0 = qt * 32;
    const size_t kvbase = ((size_t)(bi*NKV + g)) * SEQ * HD;

    // stage K rows s0-128 .. s0+159 (zeros outside sequence), XOR-swizzled chunks
    for (int slot = tid; slot < KSTG*8; slot += 512) {
        int row = slot >> 3, cc = slot & 7;
        int kpos = s0 - HALFW + row;
        h16x8 val = {0,0,0,0,0,0,0,0};
        if (kpos >= 0 && kpos < SEQ)
            val = *(const h16x8*)(kb + kvbase + (size_t)kpos*HD + cc*8);
        *(h16x8*)(Ks + row*64 + ((cc ^ (row & 7)) * 8)) = val;
    }
    // zero own wave's P pad cols [272..288)
    h16* P = Ps + wid * 16 * VSTR;
    for (int i = lane; i < 256; i += 64)
        P[(i >> 4)*VSTR + KCOLS + (i & 15)] = (h16)0;
    __syncthreads();

    const int h = g*8 + wid;
    const int colbase = lane & 15;
    const int rowbase = (lane >> 4) * 4;

    for (int strip = 0; strip < 2; ++strip) {
        const int ss0 = s0 + strip*16;
        // Q fragments straight from global
        h16x8 aq[2];
#pragma unroll
        for (int c = 0; c < 2; ++c)
            aq[c] = *(const h16x8*)(qb + ((size_t)(bi*SEQ + ss0 + colbase))*DIM
                                    + h*HD + c*32 + (lane >> 4)*8);

        // scores: 17 x 16x16 tiles over 272 keys (staged offset strip*16)
        f32x4 sc[17];
#pragma unroll
        for (int t = 0; t < 17; ++t) {
            f32x4 z = {0.f,0.f,0.f,0.f};
#pragma unroll
            for (int c = 0; c < 2; ++c) {
                int key = strip*16 + t*16 + colbase;
                h16x8 kf = *(const h16x8*)(Ks + key*64 + (((c*4 + (lane >> 4)) ^ (key & 7)) * 8));
                z = __builtin_amdgcn_mfma_f32_16x16x32_f16(aq[c], kf, z, 0, 0, 0);
            }
            sc[t] = z;
        }

        // mask (window: row <= col <= row+255) + wave-parallel softmax
        float mx[4] = {-1e30f,-1e30f,-1e30f,-1e30f};
#pragma unroll
        for (int t = 0; t < 17; ++t)
#pragma unroll
            for (int r = 0; r < 4; ++r) {
                int col = t*16 + colbase, row = rowbase + r;
                float v = (col >= row && col <= row + 255) ? sc[t][r] : -1e30f;
                sc[t][r] = v;
                mx[r] = fmaxf(mx[r], v);
            }
#pragma unroll
        for (int r = 0; r < 4; ++r) {
            mx[r] = fmaxf(mx[r], __shfl_xor(mx[r], 8));
            mx[r] = fmaxf(mx[r], __shfl_xor(mx[r], 4));
            mx[r] = fmaxf(mx[r], __shfl_xor(mx[r], 2));
            mx[r] = fmaxf(mx[r], __shfl_xor(mx[r], 1));
        }
        float sum[4] = {0.f,0.f,0.f,0.f};
#pragma unroll
        for (int t = 0; t < 17; ++t)
#pragma unroll
            for (int r = 0; r < 4; ++r) {
                float p = __expf(sc[t][r] - mx[r]);
                sc[t][r] = p;
                sum[r] += p;
            }
#pragma unroll
        for (int r = 0; r < 4; ++r) {
            sum[r] += __shfl_xor(sum[r], 8);
            sum[r] += __shfl_xor(sum[r], 4);
            sum[r] += __shfl_xor(sum[r], 2);
            sum[r] += __shfl_xor(sum[r], 1);
        }
        float inv[4];
#pragma unroll
        for (int r = 0; r < 4; ++r) inv[r] = 1.0f / sum[r];

        // write P (C-layout -> row-major [query][key]) as fp16
#pragma unroll
        for (int t = 0; t < 17; ++t)
#pragma unroll
            for (int r = 0; r < 4; ++r)
                P[(rowbase + r)*VSTR + t*16 + colbase] = (h16)(sc[t][r] * inv[r]);

        // PV: (16x288) x (288x64), V direct from global (zero outside seq/window)
        f32x4 ao[4] = {};
#pragma unroll
        for (int c = 0; c < 9; ++c) {
            h16x8 pa = *(const h16x8*)(P + colbase*VSTR + c*32 + (lane >> 4)*8);
            int col0 = c*32 + (lane >> 4)*8;
            int kp0 = ss0 - HALFW + col0;
            bool full = (col0 < KCOLS) && (kp0 >= 0) && (kp0 + 8 <= SEQ);
#pragma unroll
            for (int t2 = 0; t2 < 4; ++t2) {
                h16x8 vb;
                const h16* vrow = vtb + kvbase + (size_t)(t2*16 + colbase)*SEQ;
                if (full) {
                    vb = *(const h16x8*)(vrow + kp0);
                } else {
#pragma unroll
                    for (int j = 0; j < 8; ++j) {
                        int col = col0 + j, kp = kp0 + j;
                        vb[j] = (col < KCOLS && kp >= 0 && kp < SEQ) ? vrow[kp] : (h16)0;
                    }
                }
                ao[t2] = __builtin_amdgcn_mfma_f32_16x16x32_f16(pa, vb, ao[t2], 0, 0, 0);
            }
        }
        // epilogue: attn out [b*2048+s][h*64+d] fp16
#pragma unroll
        for (int t2 = 0; t2 < 4; ++t2)
#pragma unroll
            for (int r = 0; r < 4; ++r)
                ob[((size_t)(bi*SEQ + ss0 + rowbase + r))*DIM + h*HD + t2*16 + colbase]
                    = (h16)ao[t2][r];
    }
}

extern "C" void kernel_launch(void* const* d_in, const int* in_sizes, int n_in,
                              void* d_out, int out_size, void* d_ws, size_t ws_size,
                              hipStream_t stream)
{
    const float* x  = (const float*)d_in[0];
    const float* Wq = (const float*)d_in[1];
    const float* bq = (const float*)d_in[2];
    const float* Wk = (const float*)d_in[3];
    const float* bk = (const float*)d_in[4];
    const float* Wv = (const float*)d_in[5];
    const float* bv = (const float*)d_in[6];
    const float* Wo = (const float*)d_in[7];
    const float* bo = (const float*)d_in[8];
    float* out = (float*)d_out;
    char* ws = (char*)d_ws;

    h16*   xh    = (h16*)(ws);                 //  8388608 B  x fp16 [4096][1024]
    h16*   wqkvt = (h16*)(ws + 8388608);       //  2621440 B  Wqkv^T [1280][1024]
    h16*   wot   = (h16*)(ws + 11010048);      //  2097152 B  Wo^T [1024][1024]
    float* bqkv  = (float*)(ws + 13107200);    //     5120 B
    h16*   q_b   = (h16*)(ws + 13112320);      //  8388608 B  q [4096][1024]
    h16*   k_b   = (h16*)(ws + 21500928);      //  1048576 B  k [b][g][s][64]
    h16*   vt_b  = (h16*)(ws + 22549504);      //  1048576 B  v^T [b][g][64][s]
    h16*   att_b = (h16*)(ws + 23598080);      //  8388608 B  attn out [4096][1024]

    preprocess_kernel<<<4352, 256, 0, stream>>>(x, bq, bk, bv, Wq, Wk, Wv, Wo,
                                                xh, bqkv, wqkvt, wot);
    gemm_kernel<0><<<dim3(10,32), 256, 0, stream>>>(xh, wqkvt, bqkv,
                                                    q_b, k_b, vt_b, nullptr, DIM);
    hipFuncSetAttribute((const void*)attn_kernel,
                        hipFuncAttributeMaxDynamicSharedMemorySize, 112640);
    attn_kernel<<<dim3(64,2,2), 512, 112640, stream>>>(q_b, k_b, vt_b, att_b);
    gemm_kernel<1><<<dim3(8,32), 256, 0, stream>>>(att_b, wot, bo,
                                                   nullptr, nullptr, nullptr, out, DIM);
}

// Round 3
// 77.579 us; speedup vs baseline: 1.3002x; 1.2256x over previous
//
#include <hip/hip_runtime.h>
#include <hip/hip_fp16.h>

typedef _Float16 h16;
typedef __attribute__((ext_vector_type(8))) _Float16 h16x8;
typedef __attribute__((ext_vector_type(4))) float f32x4;

#define DIM   1024
#define SEQ   2048
#define NKV   2
#define HD    64
#define HALFW 128
#define NQKV  1280      // 1024 q + 128 k + 128 v
#define KSTG  288       // staged key rows per 32-query block
#define KCOLS 272       // keys per 16-query strip
#define VCOLS 304       // staged V cols (288 + 16 strip-1 pad overhang)
#define VSTR  312       // V / P row stride (156 words, 2-way-conflict-free)

// ---------------- fused preprocess ----------------
// blocks [0,2048): x fp32->fp16 (+bias concat)
// blocks [2048,3328): Wq|Wk|Wv transpose -> wqkvt [1280][1024] fp16
// blocks [3328,4352): Wo transpose -> wot [1024][1024] fp16
__global__ void preprocess_kernel(const float* __restrict__ x,
                                  const float* __restrict__ bq,
                                  const float* __restrict__ bk,
                                  const float* __restrict__ bv,
                                  const float* __restrict__ Wq,
                                  const float* __restrict__ Wk,
                                  const float* __restrict__ Wv,
                                  const float* __restrict__ Wo,
                                  h16* __restrict__ xh, float* __restrict__ bqkv,
                                  h16* __restrict__ wqkvt, h16* __restrict__ wot)
{
    __shared__ float tile[32][33];
    const int tid = threadIdx.x;
    const int blk = blockIdx.x;
    if (blk < 2048) {
        int i = blk * 256 + tid;
        size_t base = (size_t)i * 8;
        float4 a = *(const float4*)(x + base);
        float4 b = *(const float4*)(x + base + 4);
        h16x8 o = { (h16)a.x,(h16)a.y,(h16)a.z,(h16)a.w,
                    (h16)b.x,(h16)b.y,(h16)b.z,(h16)b.w };
        *(h16x8*)(xh + base) = o;
        if (i < NQKV) {
            float v = (i < DIM) ? bq[i] : (i < DIM+128 ? bk[i-DIM] : bv[i-DIM-128]);
            bqkv[i] = v;
        }
        return;
    }
    const int tx = tid & 31, ty = tid >> 5;
    if (blk < 2048 + 1280) {
        int bid = blk - 2048;
        int n0 = (bid % 40) * 32, k0 = (bid / 40) * 32;
        const float* src; int ldn, noff;
        if (n0 < DIM)          { src = Wq; ldn = DIM; noff = n0; }
        else if (n0 < DIM+128) { src = Wk; ldn = 128; noff = n0 - DIM; }
        else                   { src = Wv; ldn = 128; noff = n0 - DIM - 128; }
#pragma unroll
        for (int i = 0; i < 4; ++i)
            tile[ty + 8*i][tx] = src[(size_t)(k0 + ty + 8*i)*ldn + noff + tx];
        __syncthreads();
#pragma unroll
        for (int i = 0; i < 4; ++i)
            wqkvt[(size_t)(n0 + ty + 8*i)*DIM + k0 + tx] = (h16)tile[tx][ty + 8*i];
    } else {
        int bid = blk - 3328;
        int n0 = (bid % 32) * 32, k0 = (bid / 32) * 32;
#pragma unroll
        for (int i = 0; i < 4; ++i)
            tile[ty + 8*i][tx] = Wo[(size_t)(k0 + ty + 8*i)*DIM + n0 + tx];
        __syncthreads();
#pragma unroll
        for (int i = 0; i < 4; ++i)
            wot[(size_t)(n0 + ty + 8*i)*DIM + k0 + tx] = (h16)tile[tx][ty + 8*i];
    }
}

// ------------- GEMM: C = A[M][K] * Bt[N][K]^T + bias -------------
// 2-phase prefetch double-buffer (T3-minimum), BK=64, swizzled LDS,
// bijective XCD block swizzle. 1-D grid, n-tile = wg % nx.
// MODE 0: scatter epilogue -> q [m][n], k [b][g][s][d], vt [b][g][d][s], fp16
// MODE 1: fp32 out + bias
template<int MODE>
__global__ __launch_bounds__(256, 2)
void gemm_kernel(const h16* __restrict__ A, const h16* __restrict__ Bt,
                 const float* __restrict__ bias,
                 h16* __restrict__ qo, h16* __restrict__ ko, h16* __restrict__ vto,
                 float* __restrict__ co, int K, int nx)
{
    __shared__ __align__(16) h16 As[2][128*64];
    __shared__ __align__(16) h16 Bs[2][128*64];
    // bijective XCD-aware swizzle (m204)
    const int nwg = gridDim.x, bid = blockIdx.x;
    const int q8 = nwg >> 3, r8 = nwg & 7, xcd = bid & 7, off = bid >> 3;
    const int wg = (xcd < r8 ? xcd*(q8+1) : r8*(q8+1) + (xcd-r8)*q8) + off;
    const int m0 = (wg / nx) * 128, n0 = (wg % nx) * 128;
    const int tid = threadIdx.x, lane = tid & 63, wid = tid >> 6;
    const int wr = wid >> 1, wc = wid & 1;
    f32x4 acc[4][4] = {};

    auto stage = [&](int buf, int kk) {
#pragma unroll
        for (int i = 0; i < 4; ++i) {
            int slot = i*256 + tid;
            int row = slot >> 3;
            int scol = ((slot & 7) ^ (row & 7)) * 8;   // pre-swizzled source (rule 21)
            __builtin_amdgcn_global_load_lds(
                (const __attribute__((address_space(1))) void*)(A + (size_t)(m0 + row)*K + kk + scol),
                (__attribute__((address_space(3))) void*)(&As[buf][slot*8]), 16, 0, 0);
            __builtin_amdgcn_global_load_lds(
                (const __attribute__((address_space(1))) void*)(Bt + (size_t)(n0 + row)*K + kk + scol),
                (__attribute__((address_space(3))) void*)(&Bs[buf][slot*8]), 16, 0, 0);
        }
    };
    auto compute = [&](int buf) {
#pragma unroll
        for (int k2 = 0; k2 < 2; ++k2) {
            h16x8 a[4], b[4];
#pragma unroll
            for (int mi = 0; mi < 4; ++mi) {
                int row = wr*64 + mi*16 + (lane & 15);
                int cc = (k2*4 + (lane >> 4)) ^ (row & 7);
                a[mi] = *(const h16x8*)(&As[buf][row*64 + cc*8]);
            }
#pragma unroll
            for (int ni = 0; ni < 4; ++ni) {
                int row = wc*64 + ni*16 + (lane & 15);
                int cc = (k2*4 + (lane >> 4)) ^ (row & 7);
                b[ni] = *(const h16x8*)(&Bs[buf][row*64 + cc*8]);
            }
#pragma unroll
            for (int mi = 0; mi < 4; ++mi)
#pragma unroll
                for (int ni = 0; ni < 4; ++ni)
                    acc[mi][ni] = __builtin_amdgcn_mfma_f32_16x16x32_f16(a[mi], b[ni], acc[mi][ni], 0, 0, 0);
        }
    };

    stage(0, 0);
    __syncthreads();
    int cur = 0;
    for (int kk = 64; kk < K; kk += 64) {
        stage(cur ^ 1, kk);      // prefetch next tile (loads in flight across compute)
        compute(cur);
        __syncthreads();         // drains vmcnt + all waves done reading cur
        cur ^= 1;
    }
    compute(cur);

#pragma unroll
    for (int ni = 0; ni < 4; ++ni) {
        int n = n0 + wc*64 + ni*16 + (lane & 15);
        float bv = bias[n];
#pragma unroll
        for (int mi = 0; mi < 4; ++mi) {
            int mb = m0 + wr*64 + mi*16 + (lane >> 4)*4;
#pragma unroll
            for (int r = 0; r < 4; ++r) {
                int m = mb + r;
                float v = acc[mi][ni][r] + bv;
                if (MODE == 1) {
                    co[(size_t)m*DIM + n] = v;
                } else {
                    h16 hv = (h16)v;
                    if (n < DIM) {
                        qo[(size_t)m*DIM + n] = hv;
                    } else {
                        int nn = n - DIM;
                        int bi2 = m >> 11, s = m & 2047;
                        if (nn < 128) {
                            int g = nn >> 6, d = nn & 63;
                            ko[(((size_t)(bi2*NKV + g))*SEQ + s)*HD + d] = hv;
                        } else {
                            nn -= 128;
                            int g = nn >> 6, d = nn & 63;
                            vto[(((size_t)(bi2*NKV + g))*HD + d)*SEQ + s] = hv;
                        }
                    }
                }
            }
        }
    }
}

// ------------- sliding-window attention -------------
// block = (q-tile of 32, g, b) -> grid 64x2x2 = 256; 8 waves, wave = head
// K_lds [288][64] XOR-swizzled; Vt_lds [64][312] zero-padded; P per wave [16][312].
__global__ __launch_bounds__(512)
void attn_kernel(const h16* __restrict__ qb, const h16* __restrict__ kb,
                 const h16* __restrict__ vtb, h16* __restrict__ ob)
{
    extern __shared__ char smem[];
    h16* Ks  = (h16*)smem;                          // 288*64*2  = 36864 B
    h16* Vts = (h16*)(smem + 36864);                // 64*312*2  = 39936 B
    h16* Ps  = (h16*)(smem + 36864 + 39936);        // 8*16*312*2 = 79872 B
    const int tid = threadIdx.x, lane = tid & 63, wid = tid >> 6;
    const int qt = blockIdx.x, g = blockIdx.y, bi = blockIdx.z;
    const int s0 = qt * 32;
    const size_t kvbase = ((size_t)(bi*NKV + g)) * SEQ * HD;

    // stage K rows s0-128 .. s0+159 (zeros outside sequence), XOR-swizzled chunks
    for (int slot = tid; slot < KSTG*8; slot += 512) {
        int row = slot >> 3, cc = slot & 7;
        int kpos = s0 - HALFW + row;
        h16x8 val = {0,0,0,0,0,0,0,0};
        if (kpos >= 0 && kpos < SEQ)
            val = *(const h16x8*)(kb + kvbase + (size_t)kpos*HD + cc*8);
        *(h16x8*)(Ks + row*64 + ((cc ^ (row & 7)) * 8)) = val;
    }
    // stage Vt [64][304], zeros outside sequence/window
    for (int slot = tid; slot < 64*38; slot += 512) {
        int row = slot / 38, cc = slot - row*38;
        int c0 = cc * 8;
        int kp0 = s0 - HALFW + c0;
        const h16* vrow = vtb + kvbase + (size_t)row*SEQ;
        h16x8 val = {0,0,0,0,0,0,0,0};
        if (kp0 >= 0 && kp0 + 8 <= SEQ) {
            val = *(const h16x8*)(vrow + kp0);
        } else {
#pragma unroll
            for (int j = 0; j < 8; ++j) {
                int kp = kp0 + j;
                val[j] = (kp >= 0 && kp < SEQ) ? vrow[kp] : (h16)0;
            }
        }
        *(h16x8*)(Vts + row*VSTR + c0) = val;
    }
    // zero own wave's P pad cols [272..288)
    h16* P = Ps + wid * 16 * VSTR;
    for (int i = lane; i < 256; i += 64)
        P[(i >> 4)*VSTR + KCOLS + (i & 15)] = (h16)0;
    __syncthreads();

    const int h = g*8 + wid;
    const int colbase = lane & 15;
    const int rowbase = (lane >> 4) * 4;

    for (int strip = 0; strip < 2; ++strip) {
        const int ss0 = s0 + strip*16;
        // Q fragments straight from global
        h16x8 aq[2];
#pragma unroll
        for (int c = 0; c < 2; ++c)
            aq[c] = *(const h16x8*)(qb + ((size_t)(bi*SEQ + ss0 + colbase))*DIM
                                    + h*HD + c*32 + (lane >> 4)*8);

        // scores: 17 x 16x16 tiles over 272 keys (staged offset strip*16)
        f32x4 sc[17];
        __builtin_amdgcn_s_setprio(1);
#pragma unroll
        for (int t = 0; t < 17; ++t) {
            f32x4 z = {0.f,0.f,0.f,0.f};
#pragma unroll
            for (int c = 0; c < 2; ++c) {
                int key = strip*16 + t*16 + colbase;
                h16x8 kf = *(const h16x8*)(Ks + key*64 + (((c*4 + (lane >> 4)) ^ (key & 7)) * 8));
                z = __builtin_amdgcn_mfma_f32_16x16x32_f16(aq[c], kf, z, 0, 0, 0);
            }
            sc[t] = z;
        }
        __builtin_amdgcn_s_setprio(0);

        // mask only boundary tiles t=0 (col>=row) and t=16 (col<row+256)
        float mx[4];
#pragma unroll
        for (int r = 0; r < 4; ++r) {
            int row = rowbase + r;
            float v0  = (colbase >= row) ? sc[0][r]  : -1e30f;
            float v16 = (colbase <  row) ? sc[16][r] : -1e30f;
            sc[0][r] = v0; sc[16][r] = v16;
            mx[r] = fmaxf(v0, v16);
        }
#pragma unroll
        for (int t = 1; t < 16; ++t)
#pragma unroll
            for (int r = 0; r < 4; ++r) mx[r] = fmaxf(mx[r], sc[t][r]);
#pragma unroll
        for (int r = 0; r < 4; ++r) {
            mx[r] = fmaxf(mx[r], __shfl_xor(mx[r], 8));
            mx[r] = fmaxf(mx[r], __shfl_xor(mx[r], 4));
            mx[r] = fmaxf(mx[r], __shfl_xor(mx[r], 2));
            mx[r] = fmaxf(mx[r], __shfl_xor(mx[r], 1));
        }
        float sum[4] = {0.f,0.f,0.f,0.f};
#pragma unroll
        for (int t = 0; t < 17; ++t)
#pragma unroll
            for (int r = 0; r < 4; ++r) {
                float p = __expf(sc[t][r] - mx[r]);
                sc[t][r] = p;
                sum[r] += p;
            }
#pragma unroll
        for (int r = 0; r < 4; ++r) {
            sum[r] += __shfl_xor(sum[r], 8);
            sum[r] += __shfl_xor(sum[r], 4);
            sum[r] += __shfl_xor(sum[r], 2);
            sum[r] += __shfl_xor(sum[r], 1);
        }
        float inv[4];
#pragma unroll
        for (int r = 0; r < 4; ++r) inv[r] = 1.0f / sum[r];

        // write P (C-layout -> row-major [query][key]) as fp16
#pragma unroll
        for (int t = 0; t < 17; ++t)
#pragma unroll
            for (int r = 0; r < 4; ++r)
                P[(rowbase + r)*VSTR + t*16 + colbase] = (h16)(sc[t][r] * inv[r]);

        // PV: (16x288) x (288x64) from LDS
        f32x4 ao[4] = {};
        __builtin_amdgcn_s_setprio(1);
#pragma unroll
        for (int c = 0; c < 9; ++c) {
            h16x8 pa = *(const h16x8*)(P + colbase*VSTR + c*32 + (lane >> 4)*8);
            int vcol = strip*16 + c*32 + (lane >> 4)*8;
#pragma unroll
            for (int t2 = 0; t2 < 4; ++t2) {
                h16x8 vb = *(const h16x8*)(Vts + (t2*16 + colbase)*VSTR + vcol);
                ao[t2] = __builtin_amdgcn_mfma_f32_16x16x32_f16(pa, vb, ao[t2], 0, 0, 0);
            }
        }
        __builtin_amdgcn_s_setprio(0);
        // epilogue: attn out [b*2048+s][h*64+d] fp16
#pragma unroll
        for (int t2 = 0; t2 < 4; ++t2)
#pragma unroll
            for (int r = 0; r < 4; ++r)
                ob[((size_t)(bi*SEQ + ss0 + rowbase + r))*DIM + h*HD + t2*16 + colbase]
                    = (h16)ao[t2][r];
        if (strip == 0) __syncthreads();   // P reuse: wave-private, but keep waves loosely aligned
    }
}

extern "C" void kernel_launch(void* const* d_in, const int* in_sizes, int n_in,
                              void* d_out, int out_size, void* d_ws, size_t ws_size,
                              hipStream_t stream)
{
    const float* x  = (const float*)d_in[0];
    const float* Wq = (const float*)d_in[1];
    const float* bq = (const float*)d_in[2];
    const float* Wk = (const float*)d_in[3];
    const float* bk = (const float*)d_in[4];
    const float* Wv = (const float*)d_in[5];
    const float* bv = (const float*)d_in[6];
    const float* Wo = (const float*)d_in[7];
    const float* bo = (const float*)d_in[8];
    float* out = (float*)d_out;
    char* ws = (char*)d_ws;

    h16*   xh    = (h16*)(ws);                 //  8388608 B  x fp16 [4096][1024]
    h16*   wqkvt = (h16*)(ws + 8388608);       //  2621440 B  Wqkv^T [1280][1024]
    h16*   wot   = (h16*)(ws + 11010048);      //  2097152 B  Wo^T [1024][1024]
    float* bqkv  = (float*)(ws + 13107200);    //     5120 B
    h16*   q_b   = (h16*)(ws + 13112320);      //  8388608 B  q [4096][1024]
    h16*   k_b   = (h16*)(ws + 21500928);      //  1048576 B  k [b][g][s][64]
    h16*   vt_b  = (h16*)(ws + 22549504);      //  1048576 B  v^T [b][g][64][s]
    h16*   att_b = (h16*)(ws + 23598080);      //  8388608 B  attn out [4096][1024]

    preprocess_kernel<<<4352, 256, 0, stream>>>(x, bq, bk, bv, Wq, Wk, Wv, Wo,
                                                xh, bqkv, wqkvt, wot);
    gemm_kernel<0><<<320, 256, 0, stream>>>(xh, wqkvt, bqkv,
                                            q_b, k_b, vt_b, nullptr, DIM, 10);
    hipFuncSetAttribute((const void*)attn_kernel,
                        hipFuncAttributeMaxDynamicSharedMemorySize, 156672);
    attn_kernel<<<dim3(64,2,2), 512, 156672, stream>>>(q_b, k_b, vt_b, att_b);
    gemm_kernel<1><<<256, 256, 0, stream>>>(att_b, wot, bo,
                                            nullptr, nullptr, nullptr, out, DIM, 8);
}

// Round 4
// 76.202 us; speedup vs baseline: 1.3237x; 1.0181x over previous
//
#include <hip/hip_runtime.h>
#include <hip/hip_fp16.h>

typedef _Float16 h16;
typedef __attribute__((ext_vector_type(4))) _Float16 h16x4;
typedef __attribute__((ext_vector_type(8))) _Float16 h16x8;
typedef __attribute__((ext_vector_type(4))) float f32x4;

#define DIM   1024
#define SEQ   2048
#define NKV   2
#define HD    64
#define HALFW 128
#define NQKV  1280      // 1024 q + 128 k + 128 v
#define KSTG  288       // staged key rows per 32-query block
#define KCOLS 272       // keys per 16-query strip
#define VSTR  312       // V / P row stride (2-way-conflict-free)

// ---------------- fused preprocess ----------------
__global__ void preprocess_kernel(const float* __restrict__ x,
                                  const float* __restrict__ bq,
                                  const float* __restrict__ bk,
                                  const float* __restrict__ bv,
                                  const float* __restrict__ Wq,
                                  const float* __restrict__ Wk,
                                  const float* __restrict__ Wv,
                                  const float* __restrict__ Wo,
                                  h16* __restrict__ xh, float* __restrict__ bqkv,
                                  h16* __restrict__ wqkvt, h16* __restrict__ wot)
{
    __shared__ float tile[32][33];
    const int tid = threadIdx.x;
    const int blk = blockIdx.x;
    if (blk < 2048) {
        int i = blk * 256 + tid;
        size_t base = (size_t)i * 8;
        float4 a = *(const float4*)(x + base);
        float4 b = *(const float4*)(x + base + 4);
        h16x8 o = { (h16)a.x,(h16)a.y,(h16)a.z,(h16)a.w,
                    (h16)b.x,(h16)b.y,(h16)b.z,(h16)b.w };
        *(h16x8*)(xh + base) = o;
        if (i < NQKV) {
            float v = (i < DIM) ? bq[i] : (i < DIM+128 ? bk[i-DIM] : bv[i-DIM-128]);
            bqkv[i] = v;
        }
        return;
    }
    const int tx = tid & 31, ty = tid >> 5;
    if (blk < 2048 + 1280) {
        int bid = blk - 2048;
        int n0 = (bid % 40) * 32, k0 = (bid / 40) * 32;
        const float* src; int ldn, noff;
        if (n0 < DIM)          { src = Wq; ldn = DIM; noff = n0; }
        else if (n0 < DIM+128) { src = Wk; ldn = 128; noff = n0 - DIM; }
        else                   { src = Wv; ldn = 128; noff = n0 - DIM - 128; }
#pragma unroll
        for (int i = 0; i < 4; ++i)
            tile[ty + 8*i][tx] = src[(size_t)(k0 + ty + 8*i)*ldn + noff + tx];
        __syncthreads();
#pragma unroll
        for (int i = 0; i < 4; ++i)
            wqkvt[(size_t)(n0 + ty + 8*i)*DIM + k0 + tx] = (h16)tile[tx][ty + 8*i];
    } else {
        int bid = blk - 3328;
        int n0 = (bid % 32) * 32, k0 = (bid / 32) * 32;
#pragma unroll
        for (int i = 0; i < 4; ++i)
            tile[ty + 8*i][tx] = Wo[(size_t)(k0 + ty + 8*i)*DIM + n0 + tx];
        __syncthreads();
#pragma unroll
        for (int i = 0; i < 4; ++i)
            wot[(size_t)(n0 + ty + 8*i)*DIM + k0 + tx] = (h16)tile[tx][ty + 8*i];
    }
}

// ------------- GEMM: C = A[M][K] * Bt[N][K]^T + bias -------------
// 2-phase double-buffer with counted vmcnt (T4): stage(next) -> vmcnt(8) ->
// barrier -> compute(cur) -> barrier. Prefetch loads span a full iteration.
template<int MODE>
__global__ __launch_bounds__(256, 2)
void gemm_kernel(const h16* __restrict__ A, const h16* __restrict__ Bt,
                 const float* __restrict__ bias,
                 h16* __restrict__ qo, h16* __restrict__ ko, h16* __restrict__ vto,
                 float* __restrict__ co, int K, int nx)
{
    __shared__ __align__(16) h16 As[2][128*64];
    __shared__ __align__(16) h16 Bs[2][128*64];
    // bijective XCD-aware swizzle (m204)
    const int nwg = gridDim.x, bid = blockIdx.x;
    const int q8 = nwg >> 3, r8 = nwg & 7, xcd = bid & 7, off = bid >> 3;
    const int wg = (xcd < r8 ? xcd*(q8+1) : r8*(q8+1) + (xcd-r8)*q8) + off;
    const int m0 = (wg / nx) * 128, n0 = (wg % nx) * 128;
    const int tid = threadIdx.x, lane = tid & 63, wid = tid >> 6;
    const int wr = wid >> 1, wc = wid & 1;
    f32x4 acc[4][4] = {};

    auto stage = [&](int buf, int kk) {
#pragma unroll
        for (int i = 0; i < 4; ++i) {
            int slot = i*256 + tid;
            int row = slot >> 3;
            int scol = ((slot & 7) ^ (row & 7)) * 8;   // pre-swizzled source (rule 21)
            __builtin_amdgcn_global_load_lds(
                (const __attribute__((address_space(1))) void*)(A + (size_t)(m0 + row)*K + kk + scol),
                (__attribute__((address_space(3))) void*)(&As[buf][slot*8]), 16, 0, 0);
            __builtin_amdgcn_global_load_lds(
                (const __attribute__((address_space(1))) void*)(Bt + (size_t)(n0 + row)*K + kk + scol),
                (__attribute__((address_space(3))) void*)(&Bs[buf][slot*8]), 16, 0, 0);
        }
    };
    auto compute = [&](int buf) {
#pragma unroll
        for (int k2 = 0; k2 < 2; ++k2) {
            h16x8 a[4], b[4];
#pragma unroll
            for (int mi = 0; mi < 4; ++mi) {
                int row = wr*64 + mi*16 + (lane & 15);
                int cc = (k2*4 + (lane >> 4)) ^ (row & 7);
                a[mi] = *(const h16x8*)(&As[buf][row*64 + cc*8]);
            }
#pragma unroll
            for (int ni = 0; ni < 4; ++ni) {
                int row = wc*64 + ni*16 + (lane & 15);
                int cc = (k2*4 + (lane >> 4)) ^ (row & 7);
                b[ni] = *(const h16x8*)(&Bs[buf][row*64 + cc*8]);
            }
#pragma unroll
            for (int mi = 0; mi < 4; ++mi)
#pragma unroll
                for (int ni = 0; ni < 4; ++ni)
                    acc[mi][ni] = __builtin_amdgcn_mfma_f32_16x16x32_f16(a[mi], b[ni], acc[mi][ni], 0, 0, 0);
        }
    };

    const int ns = K >> 6;
    stage(0, 0);
    int cur = 0;
    for (int i = 0; i < ns; ++i) {
        if (i < ns-1) {
            stage(cur ^ 1, (i+1) << 6);                    // prefetch: 8 loads in flight
            asm volatile("s_waitcnt vmcnt(8)" ::: "memory"); // cur's loads (prev iter) landed
        } else {
            asm volatile("s_waitcnt vmcnt(0)" ::: "memory");
        }
        __builtin_amdgcn_s_barrier();
        __builtin_amdgcn_sched_barrier(0);                 // no ds_read hoisting above barrier
        compute(cur);
        if (i < ns-1) {
            __builtin_amdgcn_s_barrier();                  // all waves done reading cur
            __builtin_amdgcn_sched_barrier(0);
        }
        cur ^= 1;
    }

#pragma unroll
    for (int ni = 0; ni < 4; ++ni) {
        int n = n0 + wc*64 + ni*16 + (lane & 15);
        float bv = bias[n];
#pragma unroll
        for (int mi = 0; mi < 4; ++mi) {
            int mb = m0 + wr*64 + mi*16 + (lane >> 4)*4;
#pragma unroll
            for (int r = 0; r < 4; ++r) {
                int m = mb + r;
                float v = acc[mi][ni][r] + bv;
                if (MODE == 1) {
                    co[(size_t)m*DIM + n] = v;
                } else {
                    h16 hv = (h16)v;
                    if (n < DIM) {
                        qo[(size_t)m*DIM + n] = hv;
                    } else {
                        int nn = n - DIM;
                        int bi2 = m >> 11, s = m & 2047;
                        if (nn < 128) {
                            int g = nn >> 6, d = nn & 63;
                            ko[(((size_t)(bi2*NKV + g))*SEQ + s)*HD + d] = hv;
                        } else {
                            nn -= 128;
                            int g = nn >> 6, d = nn & 63;
                            vto[(((size_t)(bi2*NKV + g))*HD + d)*SEQ + s] = hv;
                        }
                    }
                }
            }
        }
    }
}

// ------------- sliding-window attention -------------
// Swapped QK^T: sc = mfma(K, Q) -> col=query (lane&15), row=key ((lane>>4)*4+r+16t).
// Each lane owns one query's 68-key slice: softmax reduce = 2 shuffles; P write = 17 b64.
__global__ __launch_bounds__(512)
void attn_kernel(const h16* __restrict__ qb, const h16* __restrict__ kb,
                 const h16* __restrict__ vtb, h16* __restrict__ ob)
{
    extern __shared__ char smem[];
    h16* Ks  = (h16*)smem;                          // 288*64*2  = 36864 B
    h16* Vts = (h16*)(smem + 36864);                // 64*312*2  = 39936 B
    h16* Ps  = (h16*)(smem + 36864 + 39936);        // 8*16*312*2 = 79872 B
    const int tid = threadIdx.x, lane = tid & 63, wid = tid >> 6;
    const int qt = blockIdx.x, g = blockIdx.y, bi = blockIdx.z;
    const int s0 = qt * 32;
    const size_t kvbase = ((size_t)(bi*NKV + g)) * SEQ * HD;

    // stage K rows s0-128 .. s0+159 (zeros outside sequence), XOR-swizzled chunks
    for (int slot = tid; slot < KSTG*8; slot += 512) {
        int row = slot >> 3, cc = slot & 7;
        int kpos = s0 - HALFW + row;
        h16x8 val = {0,0,0,0,0,0,0,0};
        if (kpos >= 0 && kpos < SEQ)
            val = *(const h16x8*)(kb + kvbase + (size_t)kpos*HD + cc*8);
        *(h16x8*)(Ks + row*64 + ((cc ^ (row & 7)) * 8)) = val;
    }
    // stage Vt [64][304], zeros outside sequence/window
    for (int slot = tid; slot < 64*38; slot += 512) {
        int row = slot / 38, cc = slot - row*38;
        int c0 = cc * 8;
        int kp0 = s0 - HALFW + c0;
        const h16* vrow = vtb + kvbase + (size_t)row*SEQ;
        h16x8 val = {0,0,0,0,0,0,0,0};
        if (kp0 >= 0 && kp0 + 8 <= SEQ) {
            val = *(const h16x8*)(vrow + kp0);
        } else {
#pragma unroll
            for (int j = 0; j < 8; ++j) {
                int kp = kp0 + j;
                val[j] = (kp >= 0 && kp < SEQ) ? vrow[kp] : (h16)0;
            }
        }
        *(h16x8*)(Vts + row*VSTR + c0) = val;
    }
    // zero own wave's P pad cols [272..288)
    h16* P = Ps + wid * 16 * VSTR;
    for (int i = lane; i < 256; i += 64)
        P[(i >> 4)*VSTR + KCOLS + (i & 15)] = (h16)0;
    __syncthreads();

    const int h = g*8 + wid;
    const int colbase = lane & 15;          // query (strip-local)
    const int rowbase = (lane >> 4) * 4;    // key sub-row / output row
    const int kg = rowbase;                 // key group offset within tile

    for (int strip = 0; strip < 2; ++strip) {
        const int ss0 = s0 + strip*16;
        // Q fragments straight from global (same regs serve as B-operand)
        h16x8 aq[2];
#pragma unroll
        for (int c = 0; c < 2; ++c)
            aq[c] = *(const h16x8*)(qb + ((size_t)(bi*SEQ + ss0 + colbase))*DIM
                                    + h*HD + c*32 + (lane >> 4)*8);

        // scores (swapped): sc[t][r] = score(query=colbase, key=16t+kg+r)
        f32x4 sc[17];
        __builtin_amdgcn_s_setprio(1);
#pragma unroll
        for (int t = 0; t < 17; ++t) {
            f32x4 z = {0.f,0.f,0.f,0.f};
#pragma unroll
            for (int c = 0; c < 2; ++c) {
                int key = strip*16 + t*16 + colbase;
                h16x8 kf = *(const h16x8*)(Ks + key*64 + (((c*4 + (lane >> 4)) ^ (key & 7)) * 8));
                z = __builtin_amdgcn_mfma_f32_16x16x32_f16(kf, aq[c], z, 0, 0, 0);
            }
            sc[t] = z;
        }
        __builtin_amdgcn_s_setprio(0);

        // mask boundary tiles: t=0 needs key>=q, t=16 needs key<q+256
        float mx = -1e30f;
#pragma unroll
        for (int r = 0; r < 4; ++r) {
            float v0  = (kg + r >= colbase) ? sc[0][r]  : -1e30f;
            float v16 = (kg + r <  colbase) ? sc[16][r] : -1e30f;
            sc[0][r] = v0; sc[16][r] = v16;
            mx = fmaxf(mx, fmaxf(v0, v16));
        }
#pragma unroll
        for (int t = 1; t < 16; ++t)
#pragma unroll
            for (int r = 0; r < 4; ++r) mx = fmaxf(mx, sc[t][r]);
        mx = fmaxf(mx, __shfl_xor(mx, 16));
        mx = fmaxf(mx, __shfl_xor(mx, 32));
        float sum = 0.f;
#pragma unroll
        for (int t = 0; t < 17; ++t)
#pragma unroll
            for (int r = 0; r < 4; ++r) {
                float p = __expf(sc[t][r] - mx);
                sc[t][r] = p;
                sum += p;
            }
        sum += __shfl_xor(sum, 16);
        sum += __shfl_xor(sum, 32);
        float inv = 1.0f / sum;

        // write P row=query (lane&15), 4 packed keys per tile: 17 ds_write_b64
#pragma unroll
        for (int t = 0; t < 17; ++t) {
            h16x4 pk = { (h16)(sc[t][0]*inv), (h16)(sc[t][1]*inv),
                         (h16)(sc[t][2]*inv), (h16)(sc[t][3]*inv) };
            *(h16x4*)(P + colbase*VSTR + t*16 + kg) = pk;
        }

        // PV: (16x288) x (288x64) from LDS
        f32x4 ao[4] = {};
        __builtin_amdgcn_s_setprio(1);
#pragma unroll
        for (int c = 0; c < 9; ++c) {
            h16x8 pa = *(const h16x8*)(P + colbase*VSTR + c*32 + (lane >> 4)*8);
            int vcol = strip*16 + c*32 + (lane >> 4)*8;
#pragma unroll
            for (int t2 = 0; t2 < 4; ++t2) {
                h16x8 vb = *(const h16x8*)(Vts + (t2*16 + colbase)*VSTR + vcol);
                ao[t2] = __builtin_amdgcn_mfma_f32_16x16x32_f16(pa, vb, ao[t2], 0, 0, 0);
            }
        }
        __builtin_amdgcn_s_setprio(0);
        // epilogue: attn out [b*2048+s][h*64+d] fp16
#pragma unroll
        for (int t2 = 0; t2 < 4; ++t2)
#pragma unroll
            for (int r = 0; r < 4; ++r)
                ob[((size_t)(bi*SEQ + ss0 + rowbase + r))*DIM + h*HD + t2*16 + colbase]
                    = (h16)ao[t2][r];
        if (strip == 0) __syncthreads();
    }
}

extern "C" void kernel_launch(void* const* d_in, const int* in_sizes, int n_in,
                              void* d_out, int out_size, void* d_ws, size_t ws_size,
                              hipStream_t stream)
{
    const float* x  = (const float*)d_in[0];
    const float* Wq = (const float*)d_in[1];
    const float* bq = (const float*)d_in[2];
    const float* Wk = (const float*)d_in[3];
    const float* bk = (const float*)d_in[4];
    const float* Wv = (const float*)d_in[5];
    const float* bv = (const float*)d_in[6];
    const float* Wo = (const float*)d_in[7];
    const float* bo = (const float*)d_in[8];
    float* out = (float*)d_out;
    char* ws = (char*)d_ws;

    h16*   xh    = (h16*)(ws);                 //  x fp16 [4096][1024]
    h16*   wqkvt = (h16*)(ws + 8388608);       //  Wqkv^T [1280][1024]
    h16*   wot   = (h16*)(ws + 11010048);      //  Wo^T [1024][1024]
    float* bqkv  = (float*)(ws + 13107200);
    h16*   q_b   = (h16*)(ws + 13112320);      //  q [4096][1024]
    h16*   k_b   = (h16*)(ws + 21500928);      //  k [b][g][s][64]
    h16*   vt_b  = (h16*)(ws + 22549504);      //  v^T [b][g][64][s]
    h16*   att_b = (h16*)(ws + 23598080);      //  attn out [4096][1024]

    preprocess_kernel<<<4352, 256, 0, stream>>>(x, bq, bk, bv, Wq, Wk, Wv, Wo,
                                                xh, bqkv, wqkvt, wot);
    gemm_kernel<0><<<320, 256, 0, stream>>>(xh, wqkvt, bqkv,
                                            q_b, k_b, vt_b, nullptr, DIM, 10);
    hipFuncSetAttribute((const void*)attn_kernel,
                        hipFuncAttributeMaxDynamicSharedMemorySize, 156672);
    attn_kernel<<<dim3(64,2,2), 512, 156672, stream>>>(q_b, k_b, vt_b, att_b);
    gemm_kernel<1><<<256, 256, 0, stream>>>(att_b, wot, bo,
                                            nullptr, nullptr, nullptr, out, DIM, 8);
}